// Round 1
// baseline (36.382 us; speedup 1.0000x reference)
//
#include <hip/hip_runtime.h>

#define RES 128
#define NB 16
#define NPTS (RES * RES)

// ws layout (float2 units):
//   s   : [NB][RES][RES]  offset 0            (2 MB)   sampled complex k-space
//   T   : [NB][RES][RES]  offset NB*NPTS      (2 MB)   after column (j->w) pass
//   Fy  : [RES][RES]      offset 2*NB*NPTS    (128 KB) Fy[j][w]  = exp(i*2pi/W * b_j * (w-64))
//   Fxt : [RES][RES]      offset 2*NB*NPTS+NPTS (128KB) Fxt[h][i] = exp(i*2pi/H * a_i * (h-64))

__global__ __launch_bounds__(256) void k1_sample_twiddle(
    const float* __restrict__ kin, const float* __restrict__ traj,
    float2* __restrict__ s, float2* __restrict__ Fy, float2* __restrict__ Fxt)
{
    const int blk = blockIdx.x;
    const int tid = threadIdx.x;
    const float TWO_PI = 6.283185307179586f;

    if (blk < (NB * NPTS) / 256) {            // 1024 blocks: bilinear sampling
        int gid = blk * 256 + tid;            // [0, NB*NPTS)
        int b = gid >> 14;                    // /16384
        int m = gid & (NPTS - 1);
        float tr = traj[2 * m + 0];
        float tc = traj[2 * m + 1];
        float pr = tr + 0.5f * RES;
        float pc = tc + 0.5f * RES;
        float r0f = floorf(pr);
        float c0f = floorf(pc);
        float wr = pr - r0f;
        float wc = pc - c0f;
        int r0 = (int)r0f; r0 = min(max(r0, 0), RES - 1);
        int r1 = min(r0 + 1, RES - 1);
        int c0 = (int)c0f; c0 = min(max(c0, 0), RES - 1);
        int c1 = min(c0 + 1, RES - 1);
        const float2* img = (const float2*)kin;   // [B][H][W] complex (re,im contiguous)
        float2 g00 = img[(b * RES + r0) * RES + c0];
        float2 g01 = img[(b * RES + r0) * RES + c1];
        float2 g10 = img[(b * RES + r1) * RES + c0];
        float2 g11 = img[(b * RES + r1) * RES + c1];
        float w00 = (1.f - wr) * (1.f - wc);
        float w01 = (1.f - wr) * wc;
        float w10 = wr * (1.f - wc);
        float w11 = wr * wc;
        float2 sub;
        sub.x = w00 * g00.x + w01 * g01.x + w10 * g10.x + w11 * g11.x;
        sub.y = w00 * g00.y + w01 * g01.y + w10 * g10.y + w11 * g11.y;
        s[gid] = sub;
    } else if (blk < (NB * NPTS) / 256 + NPTS / 256) {   // 64 blocks: Fy
        int e = (blk - (NB * NPTS) / 256) * 256 + tid;   // [0, NPTS)
        int j = e >> 7;
        int w = e & (RES - 1);
        float bj = traj[2 * j + 1];                      // col coord, constant over i
        float ang = (TWO_PI / RES) * bj * (float)(w - RES / 2);
        float sn, cs;
        sincosf(ang, &sn, &cs);
        Fy[e] = make_float2(cs, sn);
    } else {                                             // 64 blocks: Fxt
        int e = (blk - (NB * NPTS) / 256 - NPTS / 256) * 256 + tid;
        int h = e >> 7;
        int i = e & (RES - 1);
        float ai = traj[2 * (i * RES) + 0];              // row coord, constant over j
        float ang = (TWO_PI / RES) * ai * (float)(h - RES / 2);
        float sn, cs;
        sincosf(ang, &sn, &cs);
        Fxt[e] = make_float2(cs, sn);                    // e = h*RES + i
    }
}

// T[b,i,w] = sum_j s[b,i,j] * Fy[j,w]
__global__ __launch_bounds__(256) void k2_colpass(
    const float2* __restrict__ s, const float2* __restrict__ Fy,
    float2* __restrict__ T)
{
    __shared__ float2 sS[8][RES];   // 8 KB
    const int b  = blockIdx.x >> 4;
    const int i0 = (blockIdx.x & 15) * 8;
    const int tid = threadIdx.x;

    #pragma unroll
    for (int k = 0; k < 4; ++k) {
        int idx = tid + k * 256;          // [0,1024)
        int ii = idx >> 7;
        int j  = idx & (RES - 1);
        sS[ii][j] = s[(b * RES + i0 + ii) * RES + j];
    }
    __syncthreads();

    const int w  = tid & (RES - 1);
    const int ig = tid >> 7;              // 0/1
    float2 acc[4];
    #pragma unroll
    for (int q = 0; q < 4; ++q) acc[q] = make_float2(0.f, 0.f);

    #pragma unroll 4
    for (int j = 0; j < RES; ++j) {
        float2 fy = Fy[j * RES + w];
        #pragma unroll
        for (int q = 0; q < 4; ++q) {
            float2 sv = sS[ig * 4 + q][j];
            acc[q].x = fmaf(sv.x, fy.x, fmaf(-sv.y, fy.y, acc[q].x));
            acc[q].y = fmaf(sv.x, fy.y, fmaf( sv.y, fy.x, acc[q].y));
        }
    }

    #pragma unroll
    for (int q = 0; q < 4; ++q)
        T[(b * RES + i0 + ig * 4 + q) * RES + w] = acc[q];
}

// out[b,h,w] = sum_i Fxt[h,i] * T[b,i,w]; write [B,1,2,H,W] planes
__global__ __launch_bounds__(256) void k3_rowpass(
    const float2* __restrict__ T, const float2* __restrict__ Fxt,
    float* __restrict__ out)
{
    __shared__ float2 fS[8][RES];   // 8 KB
    const int b  = blockIdx.x >> 4;
    const int h0 = (blockIdx.x & 15) * 8;
    const int tid = threadIdx.x;

    #pragma unroll
    for (int k = 0; k < 4; ++k) {
        int idx = tid + k * 256;
        int hh = idx >> 7;
        int i  = idx & (RES - 1);
        fS[hh][i] = Fxt[(h0 + hh) * RES + i];
    }
    __syncthreads();

    const int w  = tid & (RES - 1);
    const int ig = tid >> 7;
    float2 acc[4];
    #pragma unroll
    for (int q = 0; q < 4; ++q) acc[q] = make_float2(0.f, 0.f);

    #pragma unroll 4
    for (int i = 0; i < RES; ++i) {
        float2 t = T[(b * RES + i) * RES + w];
        #pragma unroll
        for (int q = 0; q < 4; ++q) {
            float2 fx = fS[ig * 4 + q][i];
            acc[q].x = fmaf(fx.x, t.x, fmaf(-fx.y, t.y, acc[q].x));
            acc[q].y = fmaf(fx.x, t.y, fmaf( fx.y, t.x, acc[q].y));
        }
    }

    #pragma unroll
    for (int q = 0; q < 4; ++q) {
        int h = h0 + ig * 4 + q;
        out[((b * 2 + 0) * RES + h) * RES + w] = acc[q].x;
        out[((b * 2 + 1) * RES + h) * RES + w] = acc[q].y;
    }
}

extern "C" void kernel_launch(void* const* d_in, const int* in_sizes, int n_in,
                              void* d_out, int out_size, void* d_ws, size_t ws_size,
                              hipStream_t stream) {
    const float* kin  = (const float*)d_in[0];   // [16,1,128,128,2] f32
    const float* traj = (const float*)d_in[1];   // [16384,2] f32
    float* out = (float*)d_out;                  // [16,1,2,128,128] f32

    float2* ws  = (float2*)d_ws;
    float2* s   = ws;                            // NB*NPTS
    float2* T   = ws + NB * NPTS;                // NB*NPTS
    float2* Fy  = ws + 2 * NB * NPTS;            // NPTS
    float2* Fxt = ws + 2 * NB * NPTS + NPTS;     // NPTS

    const int nblk1 = (NB * NPTS) / 256 + 2 * (NPTS / 256);   // 1024 + 128
    k1_sample_twiddle<<<nblk1, 256, 0, stream>>>(kin, traj, s, Fy, Fxt);
    k2_colpass<<<NB * (RES / 8), 256, 0, stream>>>(s, Fy, T);
    k3_rowpass<<<NB * (RES / 8), 256, 0, stream>>>(T, Fxt, out);
}

// Round 2
// 35.319 us; speedup vs baseline: 1.0301x; 1.0301x over previous
//
#include <hip/hip_runtime.h>

#define RES 128
#define NB 16
#define NPTS (RES * RES)

// ws layout (float2 units):
//   T   : [NB][RES][RES]  offset 0          (2 MB)   after column (j->w) pass
//   Fy  : [RES][RES]      offset NB*NPTS    (128 KB) Fy[j][w]  = exp(i*2pi/W * b_j * (w-64))
//   Fxt : [RES][RES]      offset NB*NPTS+NPTS (128KB) Fxt[h][i] = exp(i*2pi/H * a_i * (h-64))

__device__ __forceinline__ void cmac(float2& a, float2 u, float2 v) {
    a.x = fmaf(u.x, v.x, fmaf(-u.y, v.y, a.x));
    a.y = fmaf(u.x, v.y, fmaf( u.y, v.x, a.y));
}

// 128 blocks x 256: twiddle tables only
__global__ __launch_bounds__(256) void kA_twiddle(
    const float* __restrict__ traj, float2* __restrict__ Fy, float2* __restrict__ Fxt)
{
    const float TWO_PI = 6.283185307179586f;
    int blk = blockIdx.x;
    int tid = threadIdx.x;
    if (blk < NPTS / 256) {                       // 64 blocks: Fy[j][w]
        int e = blk * 256 + tid;
        int j = e >> 7;
        int w = e & (RES - 1);
        float bj = traj[2 * j + 1];               // col coord of point (0, j)
        float ang = (TWO_PI / RES) * bj * (float)(w - RES / 2);
        float sn, cs;
        sincosf(ang, &sn, &cs);
        Fy[e] = make_float2(cs, sn);
    } else {                                      // 64 blocks: Fxt[h][i]
        int e = (blk - NPTS / 256) * 256 + tid;
        int h = e >> 7;
        int i = e & (RES - 1);
        float ai = traj[2 * (i * RES) + 0];       // row coord of point (i, 0)
        float ang = (TWO_PI / RES) * ai * (float)(h - RES / 2);
        float sn, cs;
        sincosf(ang, &sn, &cs);
        Fxt[e] = make_float2(cs, sn);             // e = h*RES + i
    }
}

// Fused bilinear-sample + column pass: T[b,i,w] = sum_j s[b,i,j] * Fy[j,w]
// 256 blocks x 512 threads; block = (b, group of 8 i-rows); thread = (g, w), 2 rows each.
__global__ __launch_bounds__(512) void kB_colpass(
    const float* __restrict__ kin, const float* __restrict__ traj,
    const float2* __restrict__ Fy, float2* __restrict__ T)
{
    __shared__ float2 sS[8][RES];   // 8 KB sampled rows
    const int b  = blockIdx.x >> 4;
    const int i0 = (blockIdx.x & 15) * 8;
    const int tid = threadIdx.x;

    const float2* img = (const float2*)kin;   // [B][H][W] complex
    #pragma unroll
    for (int k = 0; k < 2; ++k) {
        int idx = tid + k * 512;              // [0,1024)
        int ii = idx >> 7;
        int j  = idx & (RES - 1);
        int m  = (i0 + ii) * RES + j;
        float pr = traj[2 * m + 0] + 0.5f * RES;
        float pc = traj[2 * m + 1] + 0.5f * RES;
        float r0f = floorf(pr), c0f = floorf(pc);
        float wr = pr - r0f, wc = pc - c0f;
        int r0 = min(max((int)r0f, 0), RES - 1);
        int r1 = min(r0 + 1, RES - 1);
        int c0 = min(max((int)c0f, 0), RES - 1);
        int c1 = min(c0 + 1, RES - 1);
        const float2* pb = img + b * NPTS;
        float2 g00 = pb[r0 * RES + c0], g01 = pb[r0 * RES + c1];
        float2 g10 = pb[r1 * RES + c0], g11 = pb[r1 * RES + c1];
        float w00 = (1.f - wr) * (1.f - wc), w01 = (1.f - wr) * wc;
        float w10 = wr * (1.f - wc),         w11 = wr * wc;
        sS[ii][j] = make_float2(
            w00 * g00.x + w01 * g01.x + w10 * g10.x + w11 * g11.x,
            w00 * g00.y + w01 * g01.y + w10 * g10.y + w11 * g11.y);
    }
    __syncthreads();

    const int w = tid & (RES - 1);
    const int g = tid >> 7;                   // 0..3, handles rows i0+2g, i0+2g+1
    float2 a0 = make_float2(0.f, 0.f), a1 = make_float2(0.f, 0.f);

    #pragma unroll 4
    for (int j = 0; j < RES; ++j) {
        float2 fy = Fy[j * RES + w];
        float2 s0 = sS[2 * g + 0][j];
        float2 s1 = sS[2 * g + 1][j];
        cmac(a0, s0, fy);
        cmac(a1, s1, fy);
    }

    T[(b * RES + i0 + 2 * g + 0) * RES + w] = a0;
    T[(b * RES + i0 + 2 * g + 1) * RES + w] = a1;
}

// Row pass: out[b,h,w] = sum_i Fxt[h,i] * T[b,i,w]; write [B,1,2,H,W] planes
// 256 blocks x 512 threads; block = (b, group of 8 h-rows).
__global__ __launch_bounds__(512) void kC_rowpass(
    const float2* __restrict__ T, const float2* __restrict__ Fxt,
    float* __restrict__ out)
{
    __shared__ float2 fS[8][RES];   // 8 KB
    const int b  = blockIdx.x >> 4;
    const int h0 = (blockIdx.x & 15) * 8;
    const int tid = threadIdx.x;

    #pragma unroll
    for (int k = 0; k < 2; ++k) {
        int idx = tid + k * 512;
        int hh = idx >> 7;
        int i  = idx & (RES - 1);
        fS[hh][i] = Fxt[(h0 + hh) * RES + i];
    }
    __syncthreads();

    const int w = tid & (RES - 1);
    const int g = tid >> 7;                   // 0..3, handles rows h0+2g, h0+2g+1
    float2 a0 = make_float2(0.f, 0.f), a1 = make_float2(0.f, 0.f);

    #pragma unroll 4
    for (int i = 0; i < RES; ++i) {
        float2 t = T[(b * RES + i) * RES + w];
        float2 f0 = fS[2 * g + 0][i];
        float2 f1 = fS[2 * g + 1][i];
        cmac(a0, f0, t);
        cmac(a1, f1, t);
    }

    int h = h0 + 2 * g;
    out[((b * 2 + 0) * RES + h) * RES + w] = a0.x;
    out[((b * 2 + 1) * RES + h) * RES + w] = a0.y;
    out[((b * 2 + 0) * RES + h + 1) * RES + w] = a1.x;
    out[((b * 2 + 1) * RES + h + 1) * RES + w] = a1.y;
}

extern "C" void kernel_launch(void* const* d_in, const int* in_sizes, int n_in,
                              void* d_out, int out_size, void* d_ws, size_t ws_size,
                              hipStream_t stream) {
    const float* kin  = (const float*)d_in[0];   // [16,1,128,128,2] f32
    const float* traj = (const float*)d_in[1];   // [16384,2] f32
    float* out = (float*)d_out;                  // [16,1,2,128,128] f32

    float2* ws  = (float2*)d_ws;
    float2* T   = ws;                            // NB*NPTS
    float2* Fy  = ws + NB * NPTS;                // NPTS
    float2* Fxt = ws + NB * NPTS + NPTS;         // NPTS

    kA_twiddle<<<2 * (NPTS / 256), 256, 0, stream>>>(traj, Fy, Fxt);
    kB_colpass<<<NB * (RES / 8), 512, 0, stream>>>(kin, traj, Fy, T);
    kC_rowpass<<<NB * (RES / 8), 512, 0, stream>>>(T, Fxt, out);
}

// Round 3
// 29.765 us; speedup vs baseline: 1.2223x; 1.1866x over previous
//
#include <hip/hip_runtime.h>

#define RES 128
#define NB 16
#define NPTS (RES * RES)

// ws layout (float2 units):
//   T : [NB][RES][RES]  offset 0   (2 MB)  intermediate after column (j->w) pass

__device__ __forceinline__ void cmac(float2& a, float2 u, float2 v) {
    a.x = fmaf(u.x, v.x, fmaf(-u.y, v.y, a.x));
    a.y = fmaf(u.x, v.y, fmaf( u.y, v.x, a.y));
}

// Fused: bilinear sample + on-the-fly Fy twiddle + column pass
//   T[b,i,w] = sum_j s[b,i,j] * exp(i*2pi/W * b_j * (w-64)),  b_j = traj[2*j+1]
// grid 256 = (b, i0/8), block 512; thread = (g = tid>>7 in 0..3, w = tid&127), 2 rows.
__global__ __launch_bounds__(512) void kB_colpass(
    const float* __restrict__ kin, const float* __restrict__ traj,
    float2* __restrict__ T)
{
    __shared__ float2 sS[8][RES];      // 8 KB  sampled rows
    __shared__ float2 FyT[32][RES];    // 32 KB Fy tile (32 j-rows)
    const float TWO_PI = 6.283185307179586f;
    const int b  = blockIdx.x >> 4;
    const int i0 = (blockIdx.x & 15) * 8;
    const int tid = threadIdx.x;

    // ---- phase 0: bilinear sampling of 8 trajectory rows (1024 pts, 2/thread)
    const float2* img = (const float2*)kin;   // [B][H][W] complex
    #pragma unroll
    for (int k = 0; k < 2; ++k) {
        int idx = tid + k * 512;              // [0,1024)
        int ii = idx >> 7;
        int j  = idx & (RES - 1);
        int m  = (i0 + ii) * RES + j;
        float pr = traj[2 * m + 0] + 0.5f * RES;
        float pc = traj[2 * m + 1] + 0.5f * RES;
        float r0f = floorf(pr), c0f = floorf(pc);
        float wr = pr - r0f, wc = pc - c0f;
        int r0 = min(max((int)r0f, 0), RES - 1);
        int r1 = min(r0 + 1, RES - 1);
        int c0 = min(max((int)c0f, 0), RES - 1);
        int c1 = min(c0 + 1, RES - 1);
        const float2* pb = img + b * NPTS;
        float2 g00 = pb[r0 * RES + c0], g01 = pb[r0 * RES + c1];
        float2 g10 = pb[r1 * RES + c0], g11 = pb[r1 * RES + c1];
        float w00 = (1.f - wr) * (1.f - wc), w01 = (1.f - wr) * wc;
        float w10 = wr * (1.f - wc),         w11 = wr * wc;
        sS[ii][j] = make_float2(
            w00 * g00.x + w01 * g01.x + w10 * g10.x + w11 * g11.x,
            w00 * g00.y + w01 * g01.y + w10 * g10.y + w11 * g11.y);
    }
    __syncthreads();

    const int w = tid & (RES - 1);
    const int g = tid >> 7;                   // rows i0+2g, i0+2g+1
    float2 a0 = make_float2(0.f, 0.f), a1 = make_float2(0.f, 0.f);

    // thread's role in twiddle-tile computation: row jl, w-octet starting w0
    const int jl = tid >> 4;                  // 0..31
    const int w0 = (tid & 15) * 8;            // 0..120

    for (int jt = 0; jt < 4; ++jt) {
        // ---- compute Fy tile for j in [32*jt, 32*jt+32): 2 sincosf + recurrence
        float bj = traj[2 * (32 * jt + jl) + 1];
        float th = (TWO_PI / RES) * bj;
        float sn0, cs0, snr, csr;
        sincosf(th * (float)(w0 - RES / 2), &sn0, &cs0);
        sincosf(th, &snr, &csr);
        float zx = cs0, zy = sn0;
        #pragma unroll
        for (int k = 0; k < 8; ++k) {
            FyT[jl][w0 + k] = make_float2(zx, zy);
            float nx = fmaf(zx, csr, -zy * snr);
            zy = fmaf(zx, snr, zy * csr);
            zx = nx;
        }
        __syncthreads();

        // ---- accumulate 32 j-steps from LDS
        #pragma unroll 8
        for (int jj = 0; jj < 32; ++jj) {
            float2 fy = FyT[jj][w];
            float2 s0 = sS[2 * g + 0][32 * jt + jj];
            float2 s1 = sS[2 * g + 1][32 * jt + jj];
            cmac(a0, s0, fy);
            cmac(a1, s1, fy);
        }
        __syncthreads();
    }

    T[(b * RES + i0 + 2 * g + 0) * RES + w] = a0;
    T[(b * RES + i0 + 2 * g + 1) * RES + w] = a1;
}

// Row pass with in-block Fxt twiddles:
//   out[b,h,w] = sum_i exp(i*2pi/H * a_i * (h-64)) * T[b,i,w],  a_i = traj[2*(i*RES)]
// grid 256 = (b, h0/8), block 512. Output planes [B,1,2,H,W].
__global__ __launch_bounds__(512) void kC_rowpass(
    const float2* __restrict__ T, const float* __restrict__ traj,
    float* __restrict__ out)
{
    __shared__ float2 fS[8][RES];   // 8 KB
    const float TWO_PI = 6.283185307179586f;
    const int b  = blockIdx.x >> 4;
    const int h0 = (blockIdx.x & 15) * 8;
    const int tid = threadIdx.x;

    #pragma unroll
    for (int k = 0; k < 2; ++k) {
        int idx = tid + k * 512;              // [0,1024)
        int hh = idx >> 7;
        int i  = idx & (RES - 1);
        float ai = traj[2 * (i * RES) + 0];
        float ang = (TWO_PI / RES) * ai * (float)(h0 + hh - RES / 2);
        float sn, cs;
        sincosf(ang, &sn, &cs);
        fS[hh][i] = make_float2(cs, sn);
    }
    __syncthreads();

    const int w = tid & (RES - 1);
    const int g = tid >> 7;                   // rows h0+2g, h0+2g+1
    float2 a0 = make_float2(0.f, 0.f), a1 = make_float2(0.f, 0.f);

    #pragma unroll 4
    for (int i = 0; i < RES; ++i) {
        float2 t = T[(b * RES + i) * RES + w];
        float2 f0 = fS[2 * g + 0][i];
        float2 f1 = fS[2 * g + 1][i];
        cmac(a0, f0, t);
        cmac(a1, f1, t);
    }

    int h = h0 + 2 * g;
    out[((b * 2 + 0) * RES + h) * RES + w] = a0.x;
    out[((b * 2 + 1) * RES + h) * RES + w] = a0.y;
    out[((b * 2 + 0) * RES + h + 1) * RES + w] = a1.x;
    out[((b * 2 + 1) * RES + h + 1) * RES + w] = a1.y;
}

extern "C" void kernel_launch(void* const* d_in, const int* in_sizes, int n_in,
                              void* d_out, int out_size, void* d_ws, size_t ws_size,
                              hipStream_t stream) {
    const float* kin  = (const float*)d_in[0];   // [16,1,128,128,2] f32
    const float* traj = (const float*)d_in[1];   // [16384,2] f32
    float* out = (float*)d_out;                  // [16,1,2,128,128] f32

    float2* T = (float2*)d_ws;                   // NB*NPTS float2

    kB_colpass<<<NB * (RES / 8), 512, 0, stream>>>(kin, traj, T);
    kC_rowpass<<<NB * (RES / 8), 512, 0, stream>>>(T, traj, out);
}